// Round 13
// baseline (261.893 us; speedup 1.0000x reference)
//
#include <hip/hip_runtime.h>
#include <stdint.h>

#define NB 64
#define NN 1024
#define NH 256

typedef _Float16 h8v __attribute__((ext_vector_type(8)));
typedef float    f4v __attribute__((ext_vector_type(4)));
typedef uint32_t u4v __attribute__((ext_vector_type(4)));
typedef uint32_t u2v __attribute__((ext_vector_type(2)));

static __device__ __forceinline__ uint32_t pack2h(float a, float b) {
  uint32_t ua = (uint32_t)__builtin_bit_cast(uint16_t, (_Float16)a);
  uint32_t ub = (uint32_t)__builtin_bit_cast(uint16_t, (_Float16)b);
  return ua | (ub << 16);
}

static __device__ __forceinline__ void gl_lds16(const void* g, void* l) {
  __builtin_amdgcn_global_load_lds(
      (const __attribute__((address_space(1))) uint32_t*)g,
      (__attribute__((address_space(3))) uint32_t*)l, 16, 0, 0);
}

// ================= prep: build fp16 tiled images in ws (R8/R10 layout, verified) =====
// image: matrix m at m*64MB; tile (b,t) at (b*32+t)*32768
//   [0,16384): K image: 16B chunk of row k at k*512 + (X ^ ((k&7)<<4))
//   [16384,32768): V A-operand image: 16B slot at g*4096 + h*16 holding
//                  [V[4g+0..3][h], V[16+4g+0..3][h]]
__global__ __launch_bounds__(256)
void prep_tiles(const float* __restrict__ pre, const float* __restrict__ hypo,
                uint8_t* __restrict__ img)
{
  const int id = blockIdx.x;            // m*2048 + b*32 + t
  const int m  = id >> 11;
  const int bt = id & 2047;
  const float* src = (m ? hypo : pre) + (size_t)bt * (32 * NH);
  uint8_t* kimg = img + (size_t)id * 32768;
  uint8_t* vimg = kimg + 16384;

  __shared__ __align__(16) float ft[32 * 260];   // padded rows (1040 B pitch)
  const int t = threadIdx.x, w = t >> 6, lane = t & 63;

#pragma unroll
  for (int i = 0; i < 8; ++i) {
    const int row = w * 8 + i;
    gl_lds16(src + row * NH + lane * 4, (uint8_t*)ft + row * 1040);
  }
  __syncthreads();

  // K image, fully coalesced 16B writes
#pragma unroll
  for (int c = 0; c < 4; ++c) {
    const int k = c * 8 + (t >> 5);
    const uint32_t X = (uint32_t)((t & 31) * 16);
    const uint32_t h0 = ((X >> 4) ^ (uint32_t)(k & 7)) * 8;
    const uint8_t* p = (const uint8_t*)ft + k * 1040 + h0 * 4;
    f4v a0 = *(const f4v*)p;
    f4v a1 = *(const f4v*)(p + 16);
    u4v o; o[0] = pack2h(a0[0], a0[1]); o[1] = pack2h(a0[2], a0[3]);
    o[2] = pack2h(a1[0], a1[1]); o[3] = pack2h(a1[2], a1[3]);
    *(u4v*)(kimg + c * 4096 + t * 16) = o;
  }
  // V A-operand image: wave g2 owns g-block g2; coalesced 16B writes
  {
    const int g2 = t >> 6;
#pragma unroll
    for (int c = 0; c < 4; ++c) {
      const int h = c * 64 + (t & 63);
      float v[8];
#pragma unroll
      for (int j = 0; j < 4; ++j) v[j]     = ft[(4 * g2 + j) * 260 + h];
#pragma unroll
      for (int j = 0; j < 4; ++j) v[4 + j] = ft[(16 + 4 * g2 + j) * 260 + h];
      u4v o; o[0] = pack2h(v[0], v[1]); o[1] = pack2h(v[2], v[3]);
      o[2] = pack2h(v[4], v[5]); o[3] = pack2h(v[6], v[7]);
      *(u4v*)(vimg + g2 * 4096 + h * 16) = o;
    }
  }
}

// == main attention: 16 q/wave, K double-buffered + V staged under QK, 52KB LDS ==
__global__ __launch_bounds__(256, 3)
void attn_img(const uint8_t* __restrict__ img,
              const int* __restrict__ pre_mask, const int* __restrict__ hypo_mask,
              float* __restrict__ out)
{
  const int fid  = blockIdx.x;          // 0..2047
  const int xcd  = fid & 7;
  const int s    = fid >> 3;            // 0..255
  const int bp   = xcd * 16 + (s >> 4); // batch-pass 0..127
  const int rblk = s & 15;              // query block (64 rows)
  const int pass = bp >> 6;
  const int b    = bp & 63;

  const uint8_t* qimg  = img + (size_t)(pass ? 1 : 0) * 67108864;
  const uint8_t* kvimg = img + (size_t)(pass ? 0 : 1) * 67108864;
  const int* kmask = pass == 0 ? hypo_mask : pre_mask;
  const int* qmask = pass == 0 ? pre_mask  : hypo_mask;
  float* outp = out + ((size_t)pass * NB + b) * NN * NH;
  const uint8_t* kvb = kvimg + (size_t)b * (32 * 32768);
  const int* kmb = kmask + b * NN;

  __shared__ __align__(16) uint8_t kbuf[2][16384];  // K double-buffered
  __shared__ __align__(16) uint8_t vbuf[16384];     // V single (staged under QK+softmax)
  __shared__ __align__(16) float sbias[NN];         // key mask as additive bias

  const int t    = threadIdx.x;
  const int lane = t & 63;
  const int w    = t >> 6;
  const int g    = lane >> 4;
  const int q    = lane & 15;

  // key-mask -> additive bias (0 / -1e30), built once
  for (int i = t; i < NN; i += 256) sbias[i] = kmb[i] ? 0.f : -1e30f;

  // Q fragment (16 q/wave), fp16 straight from the image
  h8v qf[8];
  {
    const uint8_t* qb = qimg + (size_t)b * (32 * 32768);
    const int qrow = rblk * 64 + w * 16 + q;
    const uint8_t* qt = qb + (size_t)(qrow >> 5) * 32768 + (qrow & 31) * 512;
    const uint32_t swq = (uint32_t)((qrow & 7) << 4);
#pragma unroll
    for (int c = 0; c < 8; ++c)
      qf[c] = *(const h8v*)(qt + (((uint32_t)((c * 4 + g) << 4)) ^ swq));
  }

  f4v acc[16];
#pragma unroll
  for (int cf = 0; cf < 16; ++cf) acc[cf] = (f4v){0, 0, 0, 0};
  float mrun = -1e30f, lrun = 0.f;

  // prologue: stage K tile 0 into kbuf[0] (drained by first loop-top barrier)
#pragma unroll
  for (int i = 0; i < 4; ++i)
    gl_lds16(kvb + w * 4096 + i * 1024 + lane * 16,
             &kbuf[0][0] + w * 4096 + i * 1024);

#pragma unroll 1
  for (int kt = 0; kt < 32; ++kt) {
    __syncthreads();  // closes PV(kt-1) on vbuf; drains K(kt) stage

    // issue V(kt) and K(kt+1) stages — they fly under QK + softmax
    {
      const uint8_t* tile = kvb + (size_t)kt * 32768;
#pragma unroll
      for (int i = 0; i < 4; ++i)
        gl_lds16(tile + 16384 + w * 4096 + i * 1024 + lane * 16,
                 &vbuf[0] + w * 4096 + i * 1024);
    }
    if (kt < 31) {
      const uint8_t* ktile = kvb + (size_t)(kt + 1) * 32768;
#pragma unroll
      for (int i = 0; i < 4; ++i)
        gl_lds16(ktile + w * 4096 + i * 1024 + lane * 16,
                 &kbuf[(kt + 1) & 1][0] + w * 4096 + i * 1024);
    }

    const uint8_t* sK = &kbuf[kt & 1][0];
    const int kb = kt * 32;

    // mask bias, broadcast b128 reads (conflict-free)
    const f4v b0 = *(const f4v*)&sbias[kb + 4 * g];
    const f4v b1 = *(const f4v*)&sbias[kb + 16 + 4 * g];

    // ---- S^T = K * Q^T ----
    f4v s0 = (f4v){0, 0, 0, 0}, s1 = (f4v){0, 0, 0, 0};
    __builtin_amdgcn_s_setprio(1);
#pragma unroll
    for (int c = 0; c < 8; ++c) {
      const uint32_t a0 = (uint32_t)(q * 512) + (((uint32_t)(c * 64 + g * 16)) ^ ((uint32_t)((q & 7) << 4)));
      h8v k0 = *(const h8v*)(sK + a0);
      h8v k1 = *(const h8v*)(sK + a0 + 8192);
      s0 = __builtin_amdgcn_mfma_f32_16x16x32_f16(k0, qf[c], s0, 0, 0, 0);
      s1 = __builtin_amdgcn_mfma_f32_16x16x32_f16(k1, qf[c], s1, 0, 0, 0);
    }
    __builtin_amdgcn_s_setprio(0);

    // ---- apply bias, tile max (per query q across lanes q, q+16, q+32, q+48) ----
    f4v sb0, sb1;
#pragma unroll
    for (int r = 0; r < 4; ++r) { sb0[r] = s0[r] + b0[r]; sb1[r] = s1[r] + b1[r]; }
    float tmax = fmaxf(sb0[0], sb1[0]);
#pragma unroll
    for (int r = 1; r < 4; ++r) tmax = fmaxf(tmax, fmaxf(sb0[r], sb1[r]));
    tmax = fmaxf(tmax, __shfl_xor(tmax, 16));
    tmax = fmaxf(tmax, __shfl_xor(tmax, 32));

    // ---- T13 defer-rescale; own-lane scalar rescale (O^T layout) ----
    const bool grow = __any(tmax - mrun > 8.0f);
    if (grow) {
      const float mn = fmaxf(mrun, tmax);
      const float sc = __expf(mrun - mn);
      mrun = mn; lrun *= sc;
#pragma unroll
      for (int cf = 0; cf < 16; ++cf) {
#pragma unroll
        for (int r = 0; r < 4; ++r) acc[cf][r] *= sc;
      }
    }

    // ---- P = exp(S + bias - m): masked -> exp(-1e30) = 0 ----
    float p[8];
    float psum = 0.f;
#pragma unroll
    for (int r = 0; r < 4; ++r) {
      float p0 = __expf(sb0[r] - mrun);
      float p1 = __expf(sb1[r] - mrun);
      p[r] = p0; p[4 + r] = p1;
      psum += p0 + p1;
    }
    psum += __shfl_xor(psum, 16);
    psum += __shfl_xor(psum, 32);
    lrun += psum;

    // ---- P^T B-fragment: lane's own values, no shuffles ----
    u4v au;
    au[0] = pack2h(p[0], p[1]); au[1] = pack2h(p[2], p[3]);
    au[2] = pack2h(p[4], p[5]); au[3] = pack2h(p[6], p[7]);
    const h8v ap = __builtin_bit_cast(h8v, au);

    __syncthreads();  // drains V(kt) (+K(kt+1)); vbuf visible to all waves

    // ---- O^T += V^T * P^T ; V A-fragment b128 (bank-uniform) ----
    __builtin_amdgcn_s_setprio(1);
#pragma unroll
    for (int cf = 0; cf < 16; ++cf) {
      h8v av = *(const h8v*)(&vbuf[0] + (uint32_t)(g * 4096 + (cf * 16 + q) * 16));
      acc[cf] = __builtin_amdgcn_mfma_f32_16x16x32_f16(av, ap, acc[cf], 0, 0, 0);
    }
    __builtin_amdgcn_s_setprio(0);
  }

  // ---- epilogue: acc[cf] = O[q][cf*16+4g+0..3]; own-lane normalize; f4v stores ----
  {
    const int qrow = rblk * 64 + w * 16 + q;
    const float fac = (float)qmask[b * NN + qrow] / lrun;
    float* op = outp + (size_t)qrow * NH;
#pragma unroll
    for (int cf = 0; cf < 16; ++cf) {
      f4v v = acc[cf];
      v[0] *= fac; v[1] *= fac; v[2] *= fac; v[3] *= fac;
      *(f4v*)(op + cf * 16 + 4 * g) = v;
    }
  }
}

// ================= fallback (verified R2 kernel) =================
__global__ __launch_bounds__(256, 2)
void fused_dual_attn_fb(const float* __restrict__ pre,  const int* __restrict__ pre_mask,
                        const float* __restrict__ hypo, const int* __restrict__ hypo_mask,
                        float* __restrict__ out)
{
  const int pass = blockIdx.z;
  const float* Qm  = pass == 0 ? pre  : hypo;
  const float* KVm = pass == 0 ? hypo : pre;
  const int* kmask = pass == 0 ? hypo_mask : pre_mask;
  const int* qmask = pass == 0 ? pre_mask  : hypo_mask;
  float* outp = out + (size_t)pass * NB * NN * NH;

  const int b  = blockIdx.y;
  const int r0 = blockIdx.x * 64;

  __shared__ __align__(16) unsigned char sK [32 * NH * 2];
  __shared__ __align__(16) unsigned char sVt[NH * 16 * 4];
  __shared__ int smask[NN];

  const int t    = threadIdx.x;
  const int lane = t & 63;
  const int w    = t >> 6;
  const int g    = lane >> 4;
  const int q    = lane & 15;

  for (int i = t; i < NN; i += 256) smask[i] = kmask[b * NN + i];

  const int qrow = r0 + w * 16 + q;
  h8v qf[8];
  {
    const float* qp = Qm + ((size_t)b * NN + qrow) * NH + g * 8;
#pragma unroll
    for (int c = 0; c < 8; ++c) {
      f4v a0 = *(const f4v*)(qp + c * 32);
      f4v a1 = *(const f4v*)(qp + c * 32 + 4);
      h8v v;
      v[0] = (_Float16)a0[0]; v[1] = (_Float16)a0[1];
      v[2] = (_Float16)a0[2]; v[3] = (_Float16)a0[3];
      v[4] = (_Float16)a1[0]; v[5] = (_Float16)a1[1];
      v[6] = (_Float16)a1[2]; v[7] = (_Float16)a1[3];
      qf[c] = v;
    }
  }

  f4v acc[16];
#pragma unroll
  for (int cf = 0; cf < 16; ++cf) acc[cf] = (f4v){0.f, 0.f, 0.f, 0.f};
  float mrun = -1e30f, lrun = 0.f;

  const int skey = t & 31;
  const int m16  = (t >> 1) & 15;
  const int scb  = (t >> 5) << 2;
  const int odd  = skey & 1;

  for (int kb = 0; kb < NN; kb += 32) {
    __syncthreads();
#pragma unroll
    for (int i = 0; i < 8; ++i) {
      const int col = scb + 32 * i;
      f4v v = *(const f4v*)(KVm + ((size_t)b * NN + kb + skey) * NH + col);
      u2v d; d[0] = pack2h(v[0], v[1]); d[1] = pack2h(v[2], v[3]);
      uint32_t ka = (uint32_t)(skey * 512 + col * 2) ^ (uint32_t)((skey & 7) << 4);
      *(u2v*)(sK + ka) = d;
      float e = odd ? v[0] : v[2];
      float f = odd ? v[1] : v[3];
      float oe = __shfl_xor(e, 1);
      float of = __shfl_xor(f, 1);
      float lo0 = odd ? oe   : v[0];
      float hi0 = odd ? v[2] : oe;
      float lo1 = odd ? of   : v[1];
      float hi1 = odd ? v[3] : of;
      const int h0 = col + odd * 2;
      *(uint32_t*)(sVt + (uint32_t)((h0    ) * 64 + m16 * 4)) = pack2h(lo0, hi0);
      *(uint32_t*)(sVt + (uint32_t)((h0 + 1) * 64 + m16 * 4)) = pack2h(lo1, hi1);
    }
    __syncthreads();

    f4v s0 = (f4v){0.f,0.f,0.f,0.f}, s1 = (f4v){0.f,0.f,0.f,0.f};
#pragma unroll
    for (int c = 0; c < 8; ++c) {
      uint32_t a0 = ((uint32_t)(q * 512 + c * 64 + g * 16)) ^ (uint32_t)((q & 7) << 4);
      uint32_t a1 = ((uint32_t)((16 + q) * 512 + c * 64 + g * 16)) ^ (uint32_t)((q & 7) << 4);
      h8v k0 = *(const h8v*)(sK + a0);
      h8v k1 = *(const h8v*)(sK + a1);
      s0 = __builtin_amdgcn_mfma_f32_16x16x32_f16(k0, qf[c], s0, 0, 0, 0);
      s1 = __builtin_amdgcn_mfma_f32_16x16x32_f16(k1, qf[c], s1, 0, 0, 0);
    }

    int msk[8];
#pragma unroll
    for (int r = 0; r < 4; ++r) {
      msk[r]     = smask[kb + 4 * g + r];
      msk[4 + r] = smask[kb + 16 + 4 * g + r];
    }
    float tmax = -1e30f;
#pragma unroll
    for (int r = 0; r < 4; ++r)
      tmax = fmaxf(tmax, fmaxf(msk[r] ? s0[r] : -1e30f, msk[4 + r] ? s1[r] : -1e30f));
    tmax = fmaxf(tmax, __shfl_xor(tmax, 16));
    tmax = fmaxf(tmax, __shfl_xor(tmax, 32));
    const float mnew = fmaxf(mrun, tmax);
    const float scl = __expf(mrun - mnew);
    mrun = mnew;

    float p[8];
    float psum = 0.f;
#pragma unroll
    for (int r = 0; r < 4; ++r) {
      float p0 = msk[r]     ? __expf(s0[r] - mnew) : 0.f;
      float p1 = msk[4 + r] ? __expf(s1[r] - mnew) : 0.f;
      p[r] = p0; p[4 + r] = p1;
      psum += p0 + p1;
    }
    psum += __shfl_xor(psum, 16);
    psum += __shfl_xor(psum, 32);
    lrun = lrun * scl + psum;

    float srow[4];
#pragma unroll
    for (int r = 0; r < 4; ++r) srow[r] = __shfl(scl, 4 * g + r);
#pragma unroll
    for (int cf = 0; cf < 16; ++cf) {
#pragma unroll
      for (int r = 0; r < 4; ++r) acc[cf][r] *= srow[r];
    }

    uint32_t pf00 = pack2h(p[0], p[1]);
    uint32_t pf01 = pack2h(p[2], p[3]);
    uint32_t pf10 = pack2h(p[4], p[5]);
    uint32_t pf11 = pack2h(p[6], p[7]);
    const int srcA = q + 16 * ((2 * g) & 3);
    const int srcB = srcA + 16;
    uint32_t w0a = __shfl(pf00, srcA), w1a = __shfl(pf01, srcA);
    uint32_t w0b = __shfl(pf00, srcB), w1b = __shfl(pf01, srcB);
    uint32_t x0a = __shfl(pf10, srcA), x1a = __shfl(pf11, srcA);
    uint32_t x0b = __shfl(pf10, srcB), x1b = __shfl(pf11, srcB);
    u4v au;
    au[0] = (g >= 2) ? x0a : w0a;
    au[1] = (g >= 2) ? x1a : w1a;
    au[2] = (g >= 2) ? x0b : w0b;
    au[3] = (g >= 2) ? x1b : w1b;
    const h8v ap = __builtin_bit_cast(h8v, au);

#pragma unroll
    for (int cf = 0; cf < 16; ++cf) {
      h8v bv = *(const h8v*)(sVt + (uint32_t)((cf * 16 + q) * 64 + g * 16));
      acc[cf] = __builtin_amdgcn_mfma_f32_16x16x32_f16(ap, bv, acc[cf], 0, 0, 0);
    }
  }

  float fac[4];
#pragma unroll
  for (int r = 0; r < 4; ++r) {
    const float lr = __shfl(lrun, 4 * g + r);
    const int row = r0 + w * 16 + 4 * g + r;
    fac[r] = (float)qmask[b * NN + row] / lr;
  }
  float* op = outp + ((size_t)b * NN + r0 + w * 16) * NH;
#pragma unroll
  for (int cf = 0; cf < 16; ++cf) {
#pragma unroll
    for (int r = 0; r < 4; ++r) {
      op[(4 * g + r) * NH + cf * 16 + q] = acc[cf][r] * fac[r];
    }
  }
}

extern "C" void kernel_launch(void* const* d_in, const int* in_sizes, int n_in,
                              void* d_out, int out_size, void* d_ws, size_t ws_size,
                              hipStream_t stream) {
  const float* pre       = (const float*)d_in[0];
  const int*   pre_mask  = (const int*)d_in[1];
  const float* hypo      = (const float*)d_in[2];
  const int*   hypo_mask = (const int*)d_in[3];
  float* out = (float*)d_out;
  (void)in_sizes; (void)n_in; (void)out_size;

  if (ws_size >= (size_t)2 * 67108864) {
    uint8_t* img = (uint8_t*)d_ws;
    prep_tiles<<<dim3(4096), dim3(256), 0, stream>>>(pre, hypo, img);
    attn_img<<<dim3(2048), dim3(256), 0, stream>>>(img, pre_mask, hypo_mask, out);
  } else {
    fused_dual_attn_fb<<<dim3(16, 64, 2), dim3(256), 0, stream>>>(pre, pre_mask, hypo, hypo_mask, out);
  }
}

// Round 14
// 222.696 us; speedup vs baseline: 1.1760x; 1.1760x over previous
//
#include <hip/hip_runtime.h>
#include <stdint.h>

#define NB 64
#define NN 1024
#define NH 256

typedef _Float16 h8v __attribute__((ext_vector_type(8)));
typedef float    f4v __attribute__((ext_vector_type(4)));
typedef uint32_t u4v __attribute__((ext_vector_type(4)));
typedef uint32_t u2v __attribute__((ext_vector_type(2)));

static __device__ __forceinline__ uint32_t pack2h(float a, float b) {
  uint32_t ua = (uint32_t)__builtin_bit_cast(uint16_t, (_Float16)a);
  uint32_t ub = (uint32_t)__builtin_bit_cast(uint16_t, (_Float16)b);
  return ua | (ub << 16);
}

static __device__ __forceinline__ void gl_lds16(const void* g, void* l) {
  __builtin_amdgcn_global_load_lds(
      (const __attribute__((address_space(1))) uint32_t*)g,
      (__attribute__((address_space(3))) uint32_t*)l, 16, 0, 0);
}

// ================= prep: build fp16 tiled images in ws (R8 layout, verified) =========
// image: matrix m at m*64MB; tile (b,t) at (b*32+t)*32768
//   [0,16384): K image: 16B chunk of row k at k*512 + (X ^ ((k&7)<<4))
//   [16384,32768): V A-operand image: 16B slot at g*4096 + h*16 holding
//                  [V[4g+0..3][h], V[16+4g+0..3][h]]
__global__ __launch_bounds__(256)
void prep_tiles(const float* __restrict__ pre, const float* __restrict__ hypo,
                uint8_t* __restrict__ img)
{
  const int id = blockIdx.x;            // m*2048 + b*32 + t
  const int m  = id >> 11;
  const int bt = id & 2047;
  const float* src = (m ? hypo : pre) + (size_t)bt * (32 * NH);
  uint8_t* kimg = img + (size_t)id * 32768;
  uint8_t* vimg = kimg + 16384;

  __shared__ __align__(16) float ft[32 * 260];   // padded rows (1040 B pitch)
  const int t = threadIdx.x, w = t >> 6, lane = t & 63;

#pragma unroll
  for (int i = 0; i < 8; ++i) {
    const int row = w * 8 + i;
    gl_lds16(src + row * NH + lane * 4, (uint8_t*)ft + row * 1040);
  }
  __syncthreads();

  // K image, fully coalesced 16B writes
#pragma unroll
  for (int c = 0; c < 4; ++c) {
    const int k = c * 8 + (t >> 5);
    const uint32_t X = (uint32_t)((t & 31) * 16);
    const uint32_t h0 = ((X >> 4) ^ (uint32_t)(k & 7)) * 8;
    const uint8_t* p = (const uint8_t*)ft + k * 1040 + h0 * 4;
    f4v a0 = *(const f4v*)p;
    f4v a1 = *(const f4v*)(p + 16);
    u4v o; o[0] = pack2h(a0[0], a0[1]); o[1] = pack2h(a0[2], a0[3]);
    o[2] = pack2h(a1[0], a1[1]); o[3] = pack2h(a1[2], a1[3]);
    *(u4v*)(kimg + c * 4096 + t * 16) = o;
  }
  // V A-operand image: wave g2 owns g-block g2; coalesced 16B writes
  {
    const int g2 = t >> 6;
#pragma unroll
    for (int c = 0; c < 4; ++c) {
      const int h = c * 64 + (t & 63);
      float v[8];
#pragma unroll
      for (int j = 0; j < 4; ++j) v[j]     = ft[(4 * g2 + j) * 260 + h];
#pragma unroll
      for (int j = 0; j < 4; ++j) v[4 + j] = ft[(16 + 4 * g2 + j) * 260 + h];
      u4v o; o[0] = pack2h(v[0], v[1]); o[1] = pack2h(v[2], v[3]);
      o[2] = pack2h(v[4], v[5]); o[3] = pack2h(v[6], v[7]);
      *(u4v*)(vimg + g2 * 4096 + h * 16) = o;
    }
  }
}

// ========== main attention (R10: 32 q/wave, K+V LDS dbuf, bias mask, O^T PV) =========
__global__ __launch_bounds__(256, 2)
void attn_img(const uint8_t* __restrict__ img,
              const int* __restrict__ pre_mask, const int* __restrict__ hypo_mask,
              float* __restrict__ out)
{
  const int fid  = blockIdx.x;          // 0..1023
  const int xcd  = fid & 7;
  const int s    = fid >> 3;            // 0..127
  const int bp   = xcd * 16 + (s >> 3); // batch-pass 0..127
  const int rblk = s & 7;               // query block (128 rows)
  const int pass = bp >> 6;
  const int b    = bp & 63;

  const uint8_t* qimg  = img + (size_t)(pass ? 1 : 0) * 67108864;
  const uint8_t* kvimg = img + (size_t)(pass ? 0 : 1) * 67108864;
  const int* kmask = pass == 0 ? hypo_mask : pre_mask;
  const int* qmask = pass == 0 ? pre_mask  : hypo_mask;
  float* outp = out + ((size_t)pass * NB + b) * NN * NH;
  const uint8_t* kvb = kvimg + (size_t)b * (32 * 32768);
  const int* kmb = kmask + b * NN;

  __shared__ __align__(16) uint8_t sbuf[2][32768];   // K 16KB + V 16KB per tile
  __shared__ __align__(16) float sbias[NN];          // key mask as additive bias

  const int t    = threadIdx.x;
  const int lane = t & 63;
  const int w    = t >> 6;
  const int g    = lane >> 4;
  const int q    = lane & 15;

  // key-mask -> additive bias (0 / -1e30), built once
  for (int i = t; i < NN; i += 256) sbias[i] = kmb[i] ? 0.f : -1e30f;

  // Q fragments, fp16 straight from the image (2 frags x 8 k-chunks)
  h8v qf0[8], qf1[8];
  {
    const uint8_t* qb = qimg + (size_t)b * (32 * 32768);
#pragma unroll
    for (int ff = 0; ff < 2; ++ff) {
      const int qrow = rblk * 128 + w * 32 + ff * 16 + q;
      const uint8_t* qt = qb + (size_t)(qrow >> 5) * 32768 + (qrow & 31) * 512;
      const uint32_t swq = (uint32_t)((qrow & 7) << 4);
#pragma unroll
      for (int c = 0; c < 8; ++c) {
        h8v v = *(const h8v*)(qt + (((uint32_t)((c * 4 + g) << 4)) ^ swq));
        if (ff == 0) qf0[c] = v; else qf1[c] = v;
      }
    }
  }

  f4v accA[16], accB[16];
#pragma unroll
  for (int cf = 0; cf < 16; ++cf) { accA[cf] = (f4v){0,0,0,0}; accB[cf] = (f4v){0,0,0,0}; }
  float mrunA = -1e30f, lrunA = 0.f, mrunB = -1e30f, lrunB = 0.f;

  // prologue: stage tile 0 into buf 0 (8 x 16B per lane covers 32KB)
#pragma unroll
  for (int i = 0; i < 8; ++i)
    gl_lds16(kvb + w * 8192 + i * 1024 + lane * 16, &sbuf[0][0] + w * 8192 + i * 1024);
  __syncthreads();

#pragma unroll 1
  for (int kt = 0; kt < 32; ++kt) {
    const int cur = kt & 1;
    if (kt < 31) {
      const uint8_t* kvt = kvb + (size_t)(kt + 1) * 32768;
#pragma unroll
      for (int i = 0; i < 8; ++i)
        gl_lds16(kvt + w * 8192 + i * 1024 + lane * 16,
                 &sbuf[cur ^ 1][0] + w * 8192 + i * 1024);
    }
    const uint8_t* sK = &sbuf[cur][0];
    const uint8_t* sV = sK + 16384;
    const int kb = kt * 32;

    // mask bias, broadcast b128 reads (conflict-free)
    const f4v b0 = *(const f4v*)&sbias[kb + 4 * g];
    const f4v b1 = *(const f4v*)&sbias[kb + 16 + 4 * g];

    // ---- S^T = K * Q^T for both query fragments ----
    f4v s0A = (f4v){0,0,0,0}, s1A = (f4v){0,0,0,0};
    f4v s0B = (f4v){0,0,0,0}, s1B = (f4v){0,0,0,0};
    __builtin_amdgcn_s_setprio(1);
#pragma unroll
    for (int c = 0; c < 8; ++c) {
      const uint32_t a0 = (uint32_t)(q * 512) + (((uint32_t)(c * 64 + g * 16)) ^ ((uint32_t)((q & 7) << 4)));
      h8v k0 = *(const h8v*)(sK + a0);
      h8v k1 = *(const h8v*)(sK + a0 + 8192);
      s0A = __builtin_amdgcn_mfma_f32_16x16x32_f16(k0, qf0[c], s0A, 0, 0, 0);
      s0B = __builtin_amdgcn_mfma_f32_16x16x32_f16(k0, qf1[c], s0B, 0, 0, 0);
      s1A = __builtin_amdgcn_mfma_f32_16x16x32_f16(k1, qf0[c], s1A, 0, 0, 0);
      s1B = __builtin_amdgcn_mfma_f32_16x16x32_f16(k1, qf1[c], s1B, 0, 0, 0);
    }
    __builtin_amdgcn_s_setprio(0);

    // ---- apply bias (masked scores -> -1e30), then dual-chain tile max ----
    f4v sb0A, sb1A, sb0B, sb1B;
#pragma unroll
    for (int r = 0; r < 4; ++r) {
      sb0A[r] = s0A[r] + b0[r];  sb1A[r] = s1A[r] + b1[r];
      sb0B[r] = s0B[r] + b0[r];  sb1B[r] = s1B[r] + b1[r];
    }
    float tA = fmaxf(sb0A[0], sb1A[0]), tB = fmaxf(sb0B[0], sb1B[0]);
#pragma unroll
    for (int r = 1; r < 4; ++r) {
      tA = fmaxf(tA, fmaxf(sb0A[r], sb1A[r]));
      tB = fmaxf(tB, fmaxf(sb0B[r], sb1B[r]));
    }
    tA = fmaxf(tA, __shfl_xor(tA, 16));  tB = fmaxf(tB, __shfl_xor(tB, 16));
    tA = fmaxf(tA, __shfl_xor(tA, 32));  tB = fmaxf(tB, __shfl_xor(tB, 32));

    // ---- T13 defer-rescale; own-lane scalar rescale (O^T layout) ----
    const bool grow = __any(fmaxf(tA - mrunA, tB - mrunB) > 8.0f);
    if (grow) {
      const float mnA = fmaxf(mrunA, tA), mnB = fmaxf(mrunB, tB);
      const float sA = __expf(mrunA - mnA), sB = __expf(mrunB - mnB);
      mrunA = mnA; mrunB = mnB;
      lrunA *= sA; lrunB *= sB;
#pragma unroll
      for (int cf = 0; cf < 16; ++cf) {
#pragma unroll
        for (int r = 0; r < 4; ++r) {
          accA[cf][r] *= sA;
          accB[cf][r] *= sB;
        }
      }
    }

    // ---- P = exp(S + bias - m): masked -> exp(-1e30) = 0, no cndmask ----
    float pA[8], pB[8];
    float psA = 0.f, psB = 0.f;
#pragma unroll
    for (int r = 0; r < 4; ++r) {
      float a0 = __expf(sb0A[r] - mrunA);
      float a1 = __expf(sb1A[r] - mrunA);
      float b0e = __expf(sb0B[r] - mrunB);
      float b1e = __expf(sb1B[r] - mrunB);
      pA[r] = a0; pA[4 + r] = a1; psA += a0 + a1;
      pB[r] = b0e; pB[4 + r] = b1e; psB += b0e + b1e;
    }
    psA += __shfl_xor(psA, 16);  psB += __shfl_xor(psB, 16);
    psA += __shfl_xor(psA, 32);  psB += __shfl_xor(psB, 32);
    lrunA += psA; lrunB += psB;

    // ---- P^T B-fragments: lane's own values, no shuffles ----
    u4v au, bu;
    au[0] = pack2h(pA[0], pA[1]); au[1] = pack2h(pA[2], pA[3]);
    au[2] = pack2h(pA[4], pA[5]); au[3] = pack2h(pA[6], pA[7]);
    bu[0] = pack2h(pB[0], pB[1]); bu[1] = pack2h(pB[2], pB[3]);
    bu[2] = pack2h(pB[4], pB[5]); bu[3] = pack2h(pB[6], pB[7]);
    const h8v apA = __builtin_bit_cast(h8v, au);
    const h8v apB = __builtin_bit_cast(h8v, bu);

    // ---- O^T += V^T * P^T ; V A-fragment b128 (bank-uniform) ----
    __builtin_amdgcn_s_setprio(1);
#pragma unroll
    for (int cf = 0; cf < 16; ++cf) {
      h8v av = *(const h8v*)(sV + (uint32_t)(g * 4096 + (cf * 16 + q) * 16));
      accA[cf] = __builtin_amdgcn_mfma_f32_16x16x32_f16(av, apA, accA[cf], 0, 0, 0);
      accB[cf] = __builtin_amdgcn_mfma_f32_16x16x32_f16(av, apB, accB[cf], 0, 0, 0);
    }
    __builtin_amdgcn_s_setprio(0);

    __syncthreads();
  }

  // ---- epilogue: acc[cf] = O[q][cf*16+4g+0..3]; own-lane normalize; f4v stores ----
#pragma unroll
  for (int ff = 0; ff < 2; ++ff) {
    const float lrun = ff ? lrunB : lrunA;
    const int qrow = rblk * 128 + w * 32 + ff * 16 + q;
    const float fac = (float)qmask[b * NN + qrow] / lrun;
    float* op = outp + (size_t)qrow * NH;
#pragma unroll
    for (int cf = 0; cf < 16; ++cf) {
      f4v v = ff ? accB[cf] : accA[cf];
      v[0] *= fac; v[1] *= fac; v[2] *= fac; v[3] *= fac;
      *(f4v*)(op + cf * 16 + 4 * g) = v;
    }
  }
}

// ================= fallback (verified R2 kernel) =================
__global__ __launch_bounds__(256, 2)
void fused_dual_attn_fb(const float* __restrict__ pre,  const int* __restrict__ pre_mask,
                        const float* __restrict__ hypo, const int* __restrict__ hypo_mask,
                        float* __restrict__ out)
{
  const int pass = blockIdx.z;
  const float* Qm  = pass == 0 ? pre  : hypo;
  const float* KVm = pass == 0 ? hypo : pre;
  const int* kmask = pass == 0 ? hypo_mask : pre_mask;
  const int* qmask = pass == 0 ? pre_mask  : hypo_mask;
  float* outp = out + (size_t)pass * NB * NN * NH;

  const int b  = blockIdx.y;
  const int r0 = blockIdx.x * 64;

  __shared__ __align__(16) unsigned char sK [32 * NH * 2];
  __shared__ __align__(16) unsigned char sVt[NH * 16 * 4];
  __shared__ int smask[NN];

  const int t    = threadIdx.x;
  const int lane = t & 63;
  const int w    = t >> 6;
  const int g    = lane >> 4;
  const int q    = lane & 15;

  for (int i = t; i < NN; i += 256) smask[i] = kmask[b * NN + i];

  const int qrow = r0 + w * 16 + q;
  h8v qf[8];
  {
    const float* qp = Qm + ((size_t)b * NN + qrow) * NH + g * 8;
#pragma unroll
    for (int c = 0; c < 8; ++c) {
      f4v a0 = *(const f4v*)(qp + c * 32);
      f4v a1 = *(const f4v*)(qp + c * 32 + 4);
      h8v v;
      v[0] = (_Float16)a0[0]; v[1] = (_Float16)a0[1];
      v[2] = (_Float16)a0[2]; v[3] = (_Float16)a0[3];
      v[4] = (_Float16)a1[0]; v[5] = (_Float16)a1[1];
      v[6] = (_Float16)a1[2]; v[7] = (_Float16)a1[3];
      qf[c] = v;
    }
  }

  f4v acc[16];
#pragma unroll
  for (int cf = 0; cf < 16; ++cf) acc[cf] = (f4v){0.f, 0.f, 0.f, 0.f};
  float mrun = -1e30f, lrun = 0.f;

  const int skey = t & 31;
  const int m16  = (t >> 1) & 15;
  const int scb  = (t >> 5) << 2;
  const int odd  = skey & 1;

  for (int kb = 0; kb < NN; kb += 32) {
    __syncthreads();
#pragma unroll
    for (int i = 0; i < 8; ++i) {
      const int col = scb + 32 * i;
      f4v v = *(const f4v*)(KVm + ((size_t)b * NN + kb + skey) * NH + col);
      u2v d; d[0] = pack2h(v[0], v[1]); d[1] = pack2h(v[2], v[3]);
      uint32_t ka = (uint32_t)(skey * 512 + col * 2) ^ (uint32_t)((skey & 7) << 4);
      *(u2v*)(sK + ka) = d;
      float e = odd ? v[0] : v[2];
      float f = odd ? v[1] : v[3];
      float oe = __shfl_xor(e, 1);
      float of = __shfl_xor(f, 1);
      float lo0 = odd ? oe   : v[0];
      float hi0 = odd ? v[2] : oe;
      float lo1 = odd ? of   : v[1];
      float hi1 = odd ? v[3] : of;
      const int h0 = col + odd * 2;
      *(uint32_t*)(sVt + (uint32_t)((h0    ) * 64 + m16 * 4)) = pack2h(lo0, hi0);
      *(uint32_t*)(sVt + (uint32_t)((h0 + 1) * 64 + m16 * 4)) = pack2h(lo1, hi1);
    }
    __syncthreads();

    f4v s0 = (f4v){0.f,0.f,0.f,0.f}, s1 = (f4v){0.f,0.f,0.f,0.f};
#pragma unroll
    for (int c = 0; c < 8; ++c) {
      uint32_t a0 = ((uint32_t)(q * 512 + c * 64 + g * 16)) ^ (uint32_t)((q & 7) << 4);
      uint32_t a1 = ((uint32_t)((16 + q) * 512 + c * 64 + g * 16)) ^ (uint32_t)((q & 7) << 4);
      h8v k0 = *(const h8v*)(sK + a0);
      h8v k1 = *(const h8v*)(sK + a1);
      s0 = __builtin_amdgcn_mfma_f32_16x16x32_f16(k0, qf[c], s0, 0, 0, 0);
      s1 = __builtin_amdgcn_mfma_f32_16x16x32_f16(k1, qf[c], s1, 0, 0, 0);
    }

    int msk[8];
#pragma unroll
    for (int r = 0; r < 4; ++r) {
      msk[r]     = smask[kb + 4 * g + r];
      msk[4 + r] = smask[kb + 16 + 4 * g + r];
    }
    float tmax = -1e30f;
#pragma unroll
    for (int r = 0; r < 4; ++r)
      tmax = fmaxf(tmax, fmaxf(msk[r] ? s0[r] : -1e30f, msk[4 + r] ? s1[r] : -1e30f));
    tmax = fmaxf(tmax, __shfl_xor(tmax, 16));
    tmax = fmaxf(tmax, __shfl_xor(tmax, 32));
    const float mnew = fmaxf(mrun, tmax);
    const float scl = __expf(mrun - mnew);
    mrun = mnew;

    float p[8];
    float psum = 0.f;
#pragma unroll
    for (int r = 0; r < 4; ++r) {
      float p0 = msk[r]     ? __expf(s0[r] - mnew) : 0.f;
      float p1 = msk[4 + r] ? __expf(s1[r] - mnew) : 0.f;
      p[r] = p0; p[4 + r] = p1;
      psum += p0 + p1;
    }
    psum += __shfl_xor(psum, 16);
    psum += __shfl_xor(psum, 32);
    lrun = lrun * scl + psum;

    float srow[4];
#pragma unroll
    for (int r = 0; r < 4; ++r) srow[r] = __shfl(scl, 4 * g + r);
#pragma unroll
    for (int cf = 0; cf < 16; ++cf) {
#pragma unroll
      for (int r = 0; r < 4; ++r) acc[cf][r] *= srow[r];
    }

    uint32_t pf00 = pack2h(p[0], p[1]);
    uint32_t pf01 = pack2h(p[2], p[3]);
    uint32_t pf10 = pack2h(p[4], p[5]);
    uint32_t pf11 = pack2h(p[6], p[7]);
    const int srcA = q + 16 * ((2 * g) & 3);
    const int srcB = srcA + 16;
    uint32_t w0a = __shfl(pf00, srcA), w1a = __shfl(pf01, srcA);
    uint32_t w0b = __shfl(pf00, srcB), w1b = __shfl(pf01, srcB);
    uint32_t x0a = __shfl(pf10, srcA), x1a = __shfl(pf11, srcA);
    uint32_t x0b = __shfl(pf10, srcB), x1b = __shfl(pf11, srcB);
    u4v au;
    au[0] = (g >= 2) ? x0a : w0a;
    au[1] = (g >= 2) ? x1a : w1a;
    au[2] = (g >= 2) ? x0b : w0b;
    au[3] = (g >= 2) ? x1b : w1b;
    const h8v ap = __builtin_bit_cast(h8v, au);

#pragma unroll
    for (int cf = 0; cf < 16; ++cf) {
      h8v bv = *(const h8v*)(sVt + (uint32_t)((cf * 16 + q) * 64 + g * 16));
      acc[cf] = __builtin_amdgcn_mfma_f32_16x16x32_f16(ap, bv, acc[cf], 0, 0, 0);
    }
  }

  float fac[4];
#pragma unroll
  for (int r = 0; r < 4; ++r) {
    const float lr = __shfl(lrun, 4 * g + r);
    const int row = r0 + w * 16 + 4 * g + r;
    fac[r] = (float)qmask[b * NN + row] / lr;
  }
  float* op = outp + ((size_t)b * NN + r0 + w * 16) * NH;
#pragma unroll
  for (int cf = 0; cf < 16; ++cf) {
#pragma unroll
    for (int r = 0; r < 4; ++r) {
      op[(4 * g + r) * NH + cf * 16 + q] = acc[cf][r] * fac[r];
    }
  }
}

extern "C" void kernel_launch(void* const* d_in, const int* in_sizes, int n_in,
                              void* d_out, int out_size, void* d_ws, size_t ws_size,
                              hipStream_t stream) {
  const float* pre       = (const float*)d_in[0];
  const int*   pre_mask  = (const int*)d_in[1];
  const float* hypo      = (const float*)d_in[2];
  const int*   hypo_mask = (const int*)d_in[3];
  float* out = (float*)d_out;
  (void)in_sizes; (void)n_in; (void)out_size;

  if (ws_size >= (size_t)2 * 67108864) {
    uint8_t* img = (uint8_t*)d_ws;
    prep_tiles<<<dim3(4096), dim3(256), 0, stream>>>(pre, hypo, img);
    attn_img<<<dim3(1024), dim3(256), 0, stream>>>(img, pre_mask, hypo_mask, out);
  } else {
    fused_dual_attn_fb<<<dim3(16, 64, 2), dim3(256), 0, stream>>>(pre, pre_mask, hypo, hypo_mask, out);
  }
}

// Round 15
// 217.714 us; speedup vs baseline: 1.2029x; 1.0229x over previous
//
#include <hip/hip_runtime.h>
#include <stdint.h>

#define NB 64
#define NN 1024
#define NH 256

typedef _Float16 h8v __attribute__((ext_vector_type(8)));
typedef float    f4v __attribute__((ext_vector_type(4)));
typedef uint32_t u4v __attribute__((ext_vector_type(4)));
typedef uint32_t u2v __attribute__((ext_vector_type(2)));

static __device__ __forceinline__ uint32_t pack2h(float a, float b) {
  uint32_t ua = (uint32_t)__builtin_bit_cast(uint16_t, (_Float16)a);
  uint32_t ub = (uint32_t)__builtin_bit_cast(uint16_t, (_Float16)b);
  return ua | (ub << 16);
}

static __device__ __forceinline__ void gl_lds16(const void* g, void* l) {
  __builtin_amdgcn_global_load_lds(
      (const __attribute__((address_space(1))) uint32_t*)g,
      (__attribute__((address_space(3))) uint32_t*)l, 16, 0, 0);
}

// ================= prep: build fp16 tiled images in ws (R8 layout, verified) =========
// image: matrix m at m*64MB; tile (b,t) at (b*32+t)*32768
//   [0,16384): K image: 16B chunk of row k at k*512 + (X ^ ((k&7)<<4))
//   [16384,32768): V A-operand image: 16B slot at g*4096 + h*16 holding
//                  [V[4g+0..3][h], V[16+4g+0..3][h]]
__global__ __launch_bounds__(256)
void prep_tiles(const float* __restrict__ pre, const float* __restrict__ hypo,
                uint8_t* __restrict__ img)
{
  const int id = blockIdx.x;            // m*2048 + b*32 + t
  const int m  = id >> 11;
  const int bt = id & 2047;
  const float* src = (m ? hypo : pre) + (size_t)bt * (32 * NH);
  uint8_t* kimg = img + (size_t)id * 32768;
  uint8_t* vimg = kimg + 16384;

  __shared__ __align__(16) float ft[32 * 260];   // padded rows (1040 B pitch)
  const int t = threadIdx.x, w = t >> 6, lane = t & 63;

#pragma unroll
  for (int i = 0; i < 8; ++i) {
    const int row = w * 8 + i;
    gl_lds16(src + row * NH + lane * 4, (uint8_t*)ft + row * 1040);
  }
  __syncthreads();

  // K image, fully coalesced 16B writes
#pragma unroll
  for (int c = 0; c < 4; ++c) {
    const int k = c * 8 + (t >> 5);
    const uint32_t X = (uint32_t)((t & 31) * 16);
    const uint32_t h0 = ((X >> 4) ^ (uint32_t)(k & 7)) * 8;
    const uint8_t* p = (const uint8_t*)ft + k * 1040 + h0 * 4;
    f4v a0 = *(const f4v*)p;
    f4v a1 = *(const f4v*)(p + 16);
    u4v o; o[0] = pack2h(a0[0], a0[1]); o[1] = pack2h(a0[2], a0[3]);
    o[2] = pack2h(a1[0], a1[1]); o[3] = pack2h(a1[2], a1[3]);
    *(u4v*)(kimg + c * 4096 + t * 16) = o;
  }
  // V A-operand image: wave g2 owns g-block g2; coalesced 16B writes
  {
    const int g2 = t >> 6;
#pragma unroll
    for (int c = 0; c < 4; ++c) {
      const int h = c * 64 + (t & 63);
      float v[8];
#pragma unroll
      for (int j = 0; j < 4; ++j) v[j]     = ft[(4 * g2 + j) * 260 + h];
#pragma unroll
      for (int j = 0; j < 4; ++j) v[4 + j] = ft[(16 + 4 * g2 + j) * 260 + h];
      u4v o; o[0] = pack2h(v[0], v[1]); o[1] = pack2h(v[2], v[3]);
      o[2] = pack2h(v[4], v[5]); o[3] = pack2h(v[6], v[7]);
      *(u4v*)(vimg + g2 * 4096 + h * 16) = o;
    }
  }
}

// == main attention (R10 + deferred lrun reduction: per-lane partials, epilogue reduce) ==
__global__ __launch_bounds__(256, 2)
void attn_img(const uint8_t* __restrict__ img,
              const int* __restrict__ pre_mask, const int* __restrict__ hypo_mask,
              float* __restrict__ out)
{
  const int fid  = blockIdx.x;          // 0..1023
  const int xcd  = fid & 7;
  const int s    = fid >> 3;            // 0..127
  const int bp   = xcd * 16 + (s >> 3); // batch-pass 0..127
  const int rblk = s & 7;               // query block (128 rows)
  const int pass = bp >> 6;
  const int b    = bp & 63;

  const uint8_t* qimg  = img + (size_t)(pass ? 1 : 0) * 67108864;
  const uint8_t* kvimg = img + (size_t)(pass ? 0 : 1) * 67108864;
  const int* kmask = pass == 0 ? hypo_mask : pre_mask;
  const int* qmask = pass == 0 ? pre_mask  : hypo_mask;
  float* outp = out + ((size_t)pass * NB + b) * NN * NH;
  const uint8_t* kvb = kvimg + (size_t)b * (32 * 32768);
  const int* kmb = kmask + b * NN;

  __shared__ __align__(16) uint8_t sbuf[2][32768];   // K 16KB + V 16KB per tile
  __shared__ __align__(16) float sbias[NN];          // key mask as additive bias

  const int t    = threadIdx.x;
  const int lane = t & 63;
  const int w    = t >> 6;
  const int g    = lane >> 4;
  const int q    = lane & 15;

  // key-mask -> additive bias (0 / -1e30), built once
  for (int i = t; i < NN; i += 256) sbias[i] = kmb[i] ? 0.f : -1e30f;

  // Q fragments, fp16 straight from the image (2 frags x 8 k-chunks)
  h8v qf0[8], qf1[8];
  {
    const uint8_t* qb = qimg + (size_t)b * (32 * 32768);
#pragma unroll
    for (int ff = 0; ff < 2; ++ff) {
      const int qrow = rblk * 128 + w * 32 + ff * 16 + q;
      const uint8_t* qt = qb + (size_t)(qrow >> 5) * 32768 + (qrow & 31) * 512;
      const uint32_t swq = (uint32_t)((qrow & 7) << 4);
#pragma unroll
      for (int c = 0; c < 8; ++c) {
        h8v v = *(const h8v*)(qt + (((uint32_t)((c * 4 + g) << 4)) ^ swq));
        if (ff == 0) qf0[c] = v; else qf1[c] = v;
      }
    }
  }

  f4v accA[16], accB[16];
#pragma unroll
  for (int cf = 0; cf < 16; ++cf) { accA[cf] = (f4v){0,0,0,0}; accB[cf] = (f4v){0,0,0,0}; }
  // lrun*: PER-LANE partial sums (cross-lane reduce deferred to epilogue; the
  // rescale factor s* is uniform across each 4-lane query group, so partials
  // scale consistently)
  float mrunA = -1e30f, lrunA = 0.f, mrunB = -1e30f, lrunB = 0.f;

  // prologue: stage tile 0 into buf 0 (8 x 16B per lane covers 32KB)
#pragma unroll
  for (int i = 0; i < 8; ++i)
    gl_lds16(kvb + w * 8192 + i * 1024 + lane * 16, &sbuf[0][0] + w * 8192 + i * 1024);
  __syncthreads();

#pragma unroll 1
  for (int kt = 0; kt < 32; ++kt) {
    const int cur = kt & 1;
    if (kt < 31) {
      const uint8_t* kvt = kvb + (size_t)(kt + 1) * 32768;
#pragma unroll
      for (int i = 0; i < 8; ++i)
        gl_lds16(kvt + w * 8192 + i * 1024 + lane * 16,
                 &sbuf[cur ^ 1][0] + w * 8192 + i * 1024);
    }
    const uint8_t* sK = &sbuf[cur][0];
    const uint8_t* sV = sK + 16384;
    const int kb = kt * 32;

    // mask bias, broadcast b128 reads (conflict-free)
    const f4v b0 = *(const f4v*)&sbias[kb + 4 * g];
    const f4v b1 = *(const f4v*)&sbias[kb + 16 + 4 * g];

    // ---- S^T = K * Q^T for both query fragments ----
    f4v s0A = (f4v){0,0,0,0}, s1A = (f4v){0,0,0,0};
    f4v s0B = (f4v){0,0,0,0}, s1B = (f4v){0,0,0,0};
    __builtin_amdgcn_s_setprio(1);
#pragma unroll
    for (int c = 0; c < 8; ++c) {
      const uint32_t a0 = (uint32_t)(q * 512) + (((uint32_t)(c * 64 + g * 16)) ^ ((uint32_t)((q & 7) << 4)));
      h8v k0 = *(const h8v*)(sK + a0);
      h8v k1 = *(const h8v*)(sK + a0 + 8192);
      s0A = __builtin_amdgcn_mfma_f32_16x16x32_f16(k0, qf0[c], s0A, 0, 0, 0);
      s0B = __builtin_amdgcn_mfma_f32_16x16x32_f16(k0, qf1[c], s0B, 0, 0, 0);
      s1A = __builtin_amdgcn_mfma_f32_16x16x32_f16(k1, qf0[c], s1A, 0, 0, 0);
      s1B = __builtin_amdgcn_mfma_f32_16x16x32_f16(k1, qf1[c], s1B, 0, 0, 0);
    }
    __builtin_amdgcn_s_setprio(0);

    // ---- apply bias (masked scores -> -1e30), then dual-chain tile max ----
    f4v sb0A, sb1A, sb0B, sb1B;
#pragma unroll
    for (int r = 0; r < 4; ++r) {
      sb0A[r] = s0A[r] + b0[r];  sb1A[r] = s1A[r] + b1[r];
      sb0B[r] = s0B[r] + b0[r];  sb1B[r] = s1B[r] + b1[r];
    }
    float tA = fmaxf(sb0A[0], sb1A[0]), tB = fmaxf(sb0B[0], sb1B[0]);
#pragma unroll
    for (int r = 1; r < 4; ++r) {
      tA = fmaxf(tA, fmaxf(sb0A[r], sb1A[r]));
      tB = fmaxf(tB, fmaxf(sb0B[r], sb1B[r]));
    }
    tA = fmaxf(tA, __shfl_xor(tA, 16));  tB = fmaxf(tB, __shfl_xor(tB, 16));
    tA = fmaxf(tA, __shfl_xor(tA, 32));  tB = fmaxf(tB, __shfl_xor(tB, 32));
    // tA/tB now uniform across each 4-lane query group {q, q+16, q+32, q+48}

    // ---- T13 defer-rescale; own-lane scalar rescale (O^T layout) ----
    const bool grow = __any(fmaxf(tA - mrunA, tB - mrunB) > 8.0f);
    if (grow) {
      const float mnA = fmaxf(mrunA, tA), mnB = fmaxf(mrunB, tB);
      const float sA = __expf(mrunA - mnA), sB = __expf(mrunB - mnB);
      mrunA = mnA; mrunB = mnB;
      lrunA *= sA; lrunB *= sB;   // group-uniform scale on per-lane partials
#pragma unroll
      for (int cf = 0; cf < 16; ++cf) {
#pragma unroll
        for (int r = 0; r < 4; ++r) {
          accA[cf][r] *= sA;
          accB[cf][r] *= sB;
        }
      }
    }

    // ---- P = exp(S + bias - m); per-lane partial row sums (no in-loop shuffles) ----
    float pA[8], pB[8];
    float psA = 0.f, psB = 0.f;
#pragma unroll
    for (int r = 0; r < 4; ++r) {
      float a0 = __expf(sb0A[r] - mrunA);
      float a1 = __expf(sb1A[r] - mrunA);
      float b0e = __expf(sb0B[r] - mrunB);
      float b1e = __expf(sb1B[r] - mrunB);
      pA[r] = a0; pA[4 + r] = a1; psA += a0 + a1;
      pB[r] = b0e; pB[4 + r] = b1e; psB += b0e + b1e;
    }
    lrunA += psA; lrunB += psB;

    // ---- P^T B-fragments: lane's own values, no shuffles ----
    u4v au, bu;
    au[0] = pack2h(pA[0], pA[1]); au[1] = pack2h(pA[2], pA[3]);
    au[2] = pack2h(pA[4], pA[5]); au[3] = pack2h(pA[6], pA[7]);
    bu[0] = pack2h(pB[0], pB[1]); bu[1] = pack2h(pB[2], pB[3]);
    bu[2] = pack2h(pB[4], pB[5]); bu[3] = pack2h(pB[6], pB[7]);
    const h8v apA = __builtin_bit_cast(h8v, au);
    const h8v apB = __builtin_bit_cast(h8v, bu);

    // ---- O^T += V^T * P^T ; V A-fragment b128 (bank-uniform) ----
    __builtin_amdgcn_s_setprio(1);
#pragma unroll
    for (int cf = 0; cf < 16; ++cf) {
      h8v av = *(const h8v*)(sV + (uint32_t)(g * 4096 + (cf * 16 + q) * 16));
      accA[cf] = __builtin_amdgcn_mfma_f32_16x16x32_f16(av, apA, accA[cf], 0, 0, 0);
      accB[cf] = __builtin_amdgcn_mfma_f32_16x16x32_f16(av, apB, accB[cf], 0, 0, 0);
    }
    __builtin_amdgcn_s_setprio(0);

    __syncthreads();
  }

  // ---- epilogue: deferred cross-lane lrun reduce (2 shuffles/frag, once) ----
#pragma unroll
  for (int ff = 0; ff < 2; ++ff) {
    float lrun = ff ? lrunB : lrunA;
    lrun += __shfl_xor(lrun, 16);
    lrun += __shfl_xor(lrun, 32);
    const int qrow = rblk * 128 + w * 32 + ff * 16 + q;
    const float fac = (float)qmask[b * NN + qrow] / lrun;
    float* op = outp + (size_t)qrow * NH;
#pragma unroll
    for (int cf = 0; cf < 16; ++cf) {
      f4v v = ff ? accB[cf] : accA[cf];
      v[0] *= fac; v[1] *= fac; v[2] *= fac; v[3] *= fac;
      *(f4v*)(op + cf * 16 + 4 * g) = v;
    }
  }
}

// ================= fallback (verified R2 kernel) =================
__global__ __launch_bounds__(256, 2)
void fused_dual_attn_fb(const float* __restrict__ pre,  const int* __restrict__ pre_mask,
                        const float* __restrict__ hypo, const int* __restrict__ hypo_mask,
                        float* __restrict__ out)
{
  const int pass = blockIdx.z;
  const float* Qm  = pass == 0 ? pre  : hypo;
  const float* KVm = pass == 0 ? hypo : pre;
  const int* kmask = pass == 0 ? hypo_mask : pre_mask;
  const int* qmask = pass == 0 ? pre_mask  : hypo_mask;
  float* outp = out + (size_t)pass * NB * NN * NH;

  const int b  = blockIdx.y;
  const int r0 = blockIdx.x * 64;

  __shared__ __align__(16) unsigned char sK [32 * NH * 2];
  __shared__ __align__(16) unsigned char sVt[NH * 16 * 4];
  __shared__ int smask[NN];

  const int t    = threadIdx.x;
  const int lane = t & 63;
  const int w    = t >> 6;
  const int g    = lane >> 4;
  const int q    = lane & 15;

  for (int i = t; i < NN; i += 256) smask[i] = kmask[b * NN + i];

  const int qrow = r0 + w * 16 + q;
  h8v qf[8];
  {
    const float* qp = Qm + ((size_t)b * NN + qrow) * NH + g * 8;
#pragma unroll
    for (int c = 0; c < 8; ++c) {
      f4v a0 = *(const f4v*)(qp + c * 32);
      f4v a1 = *(const f4v*)(qp + c * 32 + 4);
      h8v v;
      v[0] = (_Float16)a0[0]; v[1] = (_Float16)a0[1];
      v[2] = (_Float16)a0[2]; v[3] = (_Float16)a0[3];
      v[4] = (_Float16)a1[0]; v[5] = (_Float16)a1[1];
      v[6] = (_Float16)a1[2]; v[7] = (_Float16)a1[3];
      qf[c] = v;
    }
  }

  f4v acc[16];
#pragma unroll
  for (int cf = 0; cf < 16; ++cf) acc[cf] = (f4v){0.f, 0.f, 0.f, 0.f};
  float mrun = -1e30f, lrun = 0.f;

  const int skey = t & 31;
  const int m16  = (t >> 1) & 15;
  const int scb  = (t >> 5) << 2;
  const int odd  = skey & 1;

  for (int kb = 0; kb < NN; kb += 32) {
    __syncthreads();
#pragma unroll
    for (int i = 0; i < 8; ++i) {
      const int col = scb + 32 * i;
      f4v v = *(const f4v*)(KVm + ((size_t)b * NN + kb + skey) * NH + col);
      u2v d; d[0] = pack2h(v[0], v[1]); d[1] = pack2h(v[2], v[3]);
      uint32_t ka = (uint32_t)(skey * 512 + col * 2) ^ (uint32_t)((skey & 7) << 4);
      *(u2v*)(sK + ka) = d;
      float e = odd ? v[0] : v[2];
      float f = odd ? v[1] : v[3];
      float oe = __shfl_xor(e, 1);
      float of = __shfl_xor(f, 1);
      float lo0 = odd ? oe   : v[0];
      float hi0 = odd ? v[2] : oe;
      float lo1 = odd ? of   : v[1];
      float hi1 = odd ? v[3] : of;
      const int h0 = col + odd * 2;
      *(uint32_t*)(sVt + (uint32_t)((h0    ) * 64 + m16 * 4)) = pack2h(lo0, hi0);
      *(uint32_t*)(sVt + (uint32_t)((h0 + 1) * 64 + m16 * 4)) = pack2h(lo1, hi1);
    }
    __syncthreads();

    f4v s0 = (f4v){0.f,0.f,0.f,0.f}, s1 = (f4v){0.f,0.f,0.f,0.f};
#pragma unroll
    for (int c = 0; c < 8; ++c) {
      uint32_t a0 = ((uint32_t)(q * 512 + c * 64 + g * 16)) ^ (uint32_t)((q & 7) << 4);
      uint32_t a1 = ((uint32_t)((16 + q) * 512 + c * 64 + g * 16)) ^ (uint32_t)((q & 7) << 4);
      h8v k0 = *(const h8v*)(sK + a0);
      h8v k1 = *(const h8v*)(sK + a1);
      s0 = __builtin_amdgcn_mfma_f32_16x16x32_f16(k0, qf[c], s0, 0, 0, 0);
      s1 = __builtin_amdgcn_mfma_f32_16x16x32_f16(k1, qf[c], s1, 0, 0, 0);
    }

    int msk[8];
#pragma unroll
    for (int r = 0; r < 4; ++r) {
      msk[r]     = smask[kb + 4 * g + r];
      msk[4 + r] = smask[kb + 16 + 4 * g + r];
    }
    float tmax = -1e30f;
#pragma unroll
    for (int r = 0; r < 4; ++r)
      tmax = fmaxf(tmax, fmaxf(msk[r] ? s0[r] : -1e30f, msk[4 + r] ? s1[r] : -1e30f));
    tmax = fmaxf(tmax, __shfl_xor(tmax, 16));
    tmax = fmaxf(tmax, __shfl_xor(tmax, 32));
    const float mnew = fmaxf(mrun, tmax);
    const float scl = __expf(mrun - mnew);
    mrun = mnew;

    float p[8];
    float psum = 0.f;
#pragma unroll
    for (int r = 0; r < 4; ++r) {
      float p0 = msk[r]     ? __expf(s0[r] - mnew) : 0.f;
      float p1 = msk[4 + r] ? __expf(s1[r] - mnew) : 0.f;
      p[r] = p0; p[4 + r] = p1;
      psum += p0 + p1;
    }
    psum += __shfl_xor(psum, 16);
    psum += __shfl_xor(psum, 32);
    lrun = lrun * scl + psum;

    float srow[4];
#pragma unroll
    for (int r = 0; r < 4; ++r) srow[r] = __shfl(scl, 4 * g + r);
#pragma unroll
    for (int cf = 0; cf < 16; ++cf) {
#pragma unroll
      for (int r = 0; r < 4; ++r) acc[cf][r] *= srow[r];
    }

    uint32_t pf00 = pack2h(p[0], p[1]);
    uint32_t pf01 = pack2h(p[2], p[3]);
    uint32_t pf10 = pack2h(p[4], p[5]);
    uint32_t pf11 = pack2h(p[6], p[7]);
    const int srcA = q + 16 * ((2 * g) & 3);
    const int srcB = srcA + 16;
    uint32_t w0a = __shfl(pf00, srcA), w1a = __shfl(pf01, srcA);
    uint32_t w0b = __shfl(pf00, srcB), w1b = __shfl(pf01, srcB);
    uint32_t x0a = __shfl(pf10, srcA), x1a = __shfl(pf11, srcA);
    uint32_t x0b = __shfl(pf10, srcB), x1b = __shfl(pf11, srcB);
    u4v au;
    au[0] = (g >= 2) ? x0a : w0a;
    au[1] = (g >= 2) ? x1a : w1a;
    au[2] = (g >= 2) ? x0b : w0b;
    au[3] = (g >= 2) ? x1b : w1b;
    const h8v ap = __builtin_bit_cast(h8v, au);

#pragma unroll
    for (int cf = 0; cf < 16; ++cf) {
      h8v bv = *(const h8v*)(sVt + (uint32_t)((cf * 16 + q) * 64 + g * 16));
      acc[cf] = __builtin_amdgcn_mfma_f32_16x16x32_f16(ap, bv, acc[cf], 0, 0, 0);
    }
  }

  float fac[4];
#pragma unroll
  for (int r = 0; r < 4; ++r) {
    const float lr = __shfl(lrun, 4 * g + r);
    const int row = r0 + w * 16 + 4 * g + r;
    fac[r] = (float)qmask[b * NN + row] / lr;
  }
  float* op = outp + ((size_t)b * NN + r0 + w * 16) * NH;
#pragma unroll
  for (int cf = 0; cf < 16; ++cf) {
#pragma unroll
    for (int r = 0; r < 4; ++r) {
      op[(4 * g + r) * NH + cf * 16 + q] = acc[cf][r] * fac[r];
    }
  }
}

extern "C" void kernel_launch(void* const* d_in, const int* in_sizes, int n_in,
                              void* d_out, int out_size, void* d_ws, size_t ws_size,
                              hipStream_t stream) {
  const float* pre       = (const float*)d_in[0];
  const int*   pre_mask  = (const int*)d_in[1];
  const float* hypo      = (const float*)d_in[2];
  const int*   hypo_mask = (const int*)d_in[3];
  float* out = (float*)d_out;
  (void)in_sizes; (void)n_in; (void)out_size;

  if (ws_size >= (size_t)2 * 67108864) {
    uint8_t* img = (uint8_t*)d_ws;
    prep_tiles<<<dim3(4096), dim3(256), 0, stream>>>(pre, hypo, img);
    attn_img<<<dim3(1024), dim3(256), 0, stream>>>(img, pre_mask, hypo_mask, out);
  } else {
    fused_dual_attn_fb<<<dim3(16, 64, 2), dim3(256), 0, stream>>>(pre, pre_mask, hypo, hypo_mask, out);
  }
}